// Round 11
// baseline (9122.591 us; speedup 1.0000x reference)
//
#include <hip/hip_runtime.h>
#include <hip/hip_bf16.h>
#include <math.h>

#define BB 32
#define T_INC 12
#define T_OUTC 12
#define NN 200
#define DIN0 2
#define HH 128
#define DHALF 64
#define NB (NN*BB)
#define XROW 256                      // fixed row stride (elems) for X planes
#define MSTRIDE ((size_t)NB*XROW)     // per-m stride in elems (u32 each: hi|lo<<16)
#define CHUNK 32                      // column chunk per gconv block
#define QT 2                          // 16-col q-tiles per chunk
#define KT2 7                         // S k-tiles: 224 = 7*32
#define RT2 13                        // S row-tiles: 208 = 13*16
#define SFRAG_PER_B ((size_t)RT2*KT2*64*8)   // elems per (mat,b)
#define PANEL_E (KT2*QT*64*8)         // 7168 bf16 per LDS panel
#define GCONV_LDS6 (6*PANEL_E*2)      // 86,016 B (X0 + T1 + T2, hi/lo)
#define GRU_ROWS 16
#define INV_SQRT_H 0.08838834764831845f

typedef __attribute__((ext_vector_type(8))) short bf16x8;
typedef __attribute__((ext_vector_type(4))) float f32x4;

__device__ __forceinline__ float sigmf(float x){ return 1.f/(1.f+expf(-x)); }
__device__ __forceinline__ float bfu(uint32_t b){ union{uint32_t u;float f;}v; v.u=b<<16; return v.f; }
__device__ __forceinline__ uint32_t fbf(float f){ union{float f2;uint32_t u;}v; v.f2=f; return (v.u + 0x7fffu + ((v.u>>16)&1u))>>16; }
// split v into bf16 hi + bf16 lo (v ~= hi + lo to ~17 mantissa bits)
__device__ __forceinline__ void splitbf(float v, uint32_t& hi, uint32_t& lo){
  hi = fbf(v);
  lo = fbf(v - bfu(hi));
}

// ---------------- prep: transpose Whh (3H x H) -> (H x 3H) ----------------
__global__ void k_whhT(const float* __restrict__ Whh, float* __restrict__ WT) {
  int idx = blockIdx.x*256 + threadIdx.x;
  if (idx >= 3*HH*HH) return;
  int i3 = idx / HH; int k = idx % HH;
  WT[(size_t)k*(3*HH) + i3] = Whh[idx];
}

// ---------------- prep: shuffle dense weights into MFMA B-fragment layout, hi/lo ----
__global__ void k_wshuf(const float* __restrict__ W, __hip_bfloat16* __restrict__ Wfh,
                        __hip_bfloat16* __restrict__ Wfl, int d, int d_pad, int OUT) {
  int idx = blockIdx.x*256 + threadIdx.x;
  int total = 5*d_pad*OUT;
  if (idx >= total) return;
  int o = idx % OUT; int tmp = idx / OUT; int k = tmp % d_pad; int m = tmp / d_pad;
  float v = (k < d) ? W[((size_t)k*5 + m)*OUT + o] : 0.f;
  int kt = k >> 5, kr = k & 31;
  int lane = ((kr>>3)<<4) | (o & 15);
  int j = kr & 7;
  int nt = o >> 4;
  int KT = d_pad >> 5, NT = OUT >> 4;
  size_t addr = ((((size_t)m*KT + kt)*NT + nt)*64 + (size_t)lane)*8 + j;
  uint32_t hi, lo; splitbf(v, hi, lo);
  Wfh[addr] = *(__hip_bfloat16*)&hi;
  Wfl[addr] = *(__hip_bfloat16*)&lo;
}

// ---------------- prep: shuffle S1/S2 (dense, from adj) into A-frag layout, hi/lo ----
// s1[n][j] = adj[j][n]/rs[j] ; s2[n][j] = adj[n][j]/cs[j] ; padded to 208x224
__global__ void k_sshuf(const float* __restrict__ adj, const float* __restrict__ rs,
                        const float* __restrict__ cs,
                        __hip_bfloat16* __restrict__ SFH, __hip_bfloat16* __restrict__ SFL) {
  const int PER_B = 208*224;
  int idx = blockIdx.x*256 + threadIdx.x;
  if (idx >= 2*BB*PER_B) return;
  int e = idx % PER_B; int t2 = idx / PER_B; int b = t2 % BB; int mat = t2 / BB;
  int n = e / 224; int j = e % 224;
  float v = 0.f;
  if (n < NN && j < NN) {
    if (mat == 0) v = adj[((size_t)b*NN + j)*NN + n] / rs[(size_t)b*NN + j];
    else          v = adj[((size_t)b*NN + n)*NN + j] / cs[(size_t)b*NN + j];
  }
  int rt = n >> 4, rr = n & 15, kt = j >> 5, kr = j & 31;
  int lane = ((kr >> 3) << 4) | rr;
  int jj = kr & 7;
  size_t addr = ((size_t)(mat*BB + b)*RT2*KT2 + (size_t)(rt*KT2 + kt))*512
              + (size_t)lane*8 + jj;
  uint32_t hi, lo; splitbf(v, hi, lo);
  SFH[addr] = *(__hip_bfloat16*)&hi;
  SFL[addr] = *(__hip_bfloat16*)&lo;
}

// ---------------- GRU, all 12 steps fused; 16 rows/block, 4 rows/thread ------------
// Thread (g,i): rows row0 + g + 4j (j=0..3), element i. 12 FMA per 3 weight loads.
__global__ __launch_bounds__(512) void k_gru_all(
    const float* __restrict__ enc_in, const float* __restrict__ Wih,
    const float* __restrict__ WhhT, const float* __restrict__ bih,
    const float* __restrict__ bhh, float* __restrict__ outs) {
  int row0 = blockIdx.x * GRU_ROWS;
  int tid = threadIdx.x;
  int g = tid >> 7;                    // 0..3
  int i = tid & 127;
  __shared__ float hs[GRU_ROWS][HH];
  #pragma unroll
  for (int j=0;j<4;j++) hs[g+4*j][i] = 0.f;
  float wi0 = Wih[(0*HH+i)*2+0], wi1 = Wih[(0*HH+i)*2+1];
  float wz0 = Wih[(1*HH+i)*2+0], wz1 = Wih[(1*HH+i)*2+1];
  float wg0 = Wih[(2*HH+i)*2+0], wg1 = Wih[(2*HH+i)*2+1];
  float bi = bih[i], bz = bih[HH+i], bg = bih[2*HH+i];
  float bhr = bhh[i], bhz = bhh[HH+i], bhg = bhh[2*HH+i];
  int nn_[4], bb_[4];
  #pragma unroll
  for (int j=0;j<4;j++) { int r = row0 + g + 4*j; nn_[j] = r / BB; bb_[j] = r % BB; }
  for (int t=0;t<T_INC;t++) {
    __syncthreads();
    float hr[4], hz[4], hg[4], ii_[4], iz_[4], ig_[4];
    #pragma unroll
    for (int j=0;j<4;j++) {
      float x0 = enc_in[(((size_t)bb_[j]*T_INC + t)*NN + nn_[j])*DIN0 + 0];
      float x1 = enc_in[(((size_t)bb_[j]*T_INC + t)*NN + nn_[j])*DIN0 + 1];
      ii_[j] = wi0*x0 + wi1*x1 + bi;
      iz_[j] = wz0*x0 + wz1*x1 + bz;
      ig_[j] = wg0*x0 + wg1*x1 + bg;
      hr[j] = bhr; hz[j] = bhz; hg[j] = bhg;
    }
    for (int k=0;k<HH;k++) {
      const float* wr = WhhT + (size_t)k*(3*HH);
      float w0 = wr[i], w1 = wr[i+128], w2 = wr[i+256];
      #pragma unroll
      for (int j=0;j<4;j++) {
        float hv = hs[g+4*j][k];
        hr[j] += w0*hv; hz[j] += w1*hv; hg[j] += w2*hv;
      }
    }
    float hn[4];
    #pragma unroll
    for (int j=0;j<4;j++) {
      float r = sigmf(ii_[j]+hr[j]);
      float z = sigmf(iz_[j]+hz[j]);
      float nn2 = tanhf(ig_[j] + r*hg[j]);
      hn[j] = (1.f-z)*nn2 + z*hs[g+4*j][i];
    }
    __syncthreads();
    #pragma unroll
    for (int j=0;j<4;j++) {
      hs[g+4*j][i] = hn[j];
      outs[(((size_t)t*NN+nn_[j])*BB+bb_[j])*HH + i] = hn[j];
    }
  }
}

// ---------------- length-attention pooling (256 thr, LDS-staged attW) ---------------
__global__ __launch_bounds__(256) void k_att_pool(
    const float* __restrict__ outs, const float* __restrict__ attW,
    const float* __restrict__ attb, const float* __restrict__ wlc,
    float* __restrict__ pooled) {
  int row = blockIdx.x; int n = row / BB, b = row % BB;
  int tid = threadIdx.x;
  __shared__ float o_s[T_INC][HH];
  __shared__ float aw[DHALF][HH+1];
  __shared__ float pt[T_INC];
  for (int i = tid; i < T_INC*HH; i += 256) {
    int t = i >> 7, k = i & 127;
    o_s[t][k] = outs[(((size_t)t*NN+n)*BB+b)*HH + k];
  }
  for (int i = tid; i < DHALF*HH; i += 256) {
    int d2 = i >> 7, k = i & 127;
    aw[d2][k] = attW[(size_t)d2*HH + k];
  }
  __syncthreads();
  int d = tid & 63, tq = tid >> 6;
  float ab = attb[d], wc = wlc[d];
  float part[3];
  #pragma unroll
  for (int j=0;j<3;j++) {
    int t = tq + j*4;
    float acc = ab;
    for (int k=0;k<HH;k++) acc += aw[d][k]*o_s[t][k];
    part[j] = fmaxf(acc, 0.f)*wc;
  }
  for (int off=32; off; off>>=1)
    #pragma unroll
    for (int j=0;j<3;j++) part[j] += __shfl_xor(part[j], off, 64);
  if (d == 0) { pt[tq] = part[0]; pt[tq+4] = part[1]; pt[tq+8] = part[2]; }
  __syncthreads();
  float mx = -1e30f;
  for (int t=0;t<T_INC;t++) mx = fmaxf(mx, pt[t]);
  float e[T_INC]; float s = 0.f;
  for (int t=0;t<T_INC;t++) { e[t] = expf(pt[t]-mx); s += e[t]; }
  float inv = 1.f/s;
  for (int k=tid;k<HH;k+=256) {
    float acc = 0.f;
    for (int t=0;t<T_INC;t++) acc += o_s[t][k]*e[t];
    pooled[((size_t)b*NN+n)*HH + k] = acc*inv;
  }
}

// ---------------- key/query projections ----------------
__global__ void k_keyquery(const float* __restrict__ pooled, const float* __restrict__ wkey,
                           const float* __restrict__ wqry, float* __restrict__ keym,
                           float* __restrict__ qm) {
  int bn = blockIdx.x; int lane = threadIdx.x; // 64
  __shared__ float p_s[HH];
  p_s[lane] = pooled[(size_t)bn*HH + lane];
  p_s[lane+64] = pooled[(size_t)bn*HH + lane + 64];
  __syncthreads();
  float ka = 0.f, qa = 0.f;
  for (int k=0;k<HH;k++) {
    float pv = p_s[k];
    ka += pv*wkey[(size_t)k*DHALF + lane];
    qa += pv*wqry[(size_t)k*DHALF + lane];
  }
  keym[(size_t)bn*DHALF + lane] = ka;
  qm[(size_t)bn*DHALF + lane] = qa;
}

// ---------------- attention row -> softmax -> topk -> adj row + rowsum ----------------
__global__ void k_attn_row(const float* __restrict__ keym, const float* __restrict__ qm,
                           const int* __restrict__ topkp, float* __restrict__ adj,
                           float* __restrict__ rowsum) {
  int bn = blockIdx.x; int b = bn / NN; int n = bn % NN;
  int tid = threadIdx.x; // 256
  __shared__ float key_s[DHALF];
  __shared__ float attv[256];
  __shared__ float red[256];
  __shared__ int redi[256];
  if (tid < DHALF) key_s[tid] = keym[(size_t)bn*DHALF + tid];
  __syncthreads();
  float sc = -1e30f;
  if (tid < NN) {
    float a = 0.f;
    const float* qrow = qm + ((size_t)b*NN + tid)*DHALF;
    for (int k=0;k<DHALF;k++) a += key_s[k]*qrow[k];
    sc = a * INV_SQRT_H;
  }
  red[tid] = sc; __syncthreads();
  for (int s=128;s>0;s>>=1){ if (tid<s) red[tid]=fmaxf(red[tid],red[tid+s]); __syncthreads(); }
  float mx = red[0]; __syncthreads();
  float e = (tid<NN) ? expf(sc-mx) : 0.f;
  red[tid] = e; __syncthreads();
  for (int s=128;s>0;s>>=1){ if (tid<s) red[tid]+=red[tid+s]; __syncthreads(); }
  float inv = 1.f/red[0]; __syncthreads();
  float av = e*inv;
  attv[tid] = (tid<NN) ? av : -1e30f;
  __syncthreads();
  int Ks = topkp[0]; if (Ks > NN) Ks = NN;
  float kth = -1e30f;
  for (int it=0; it<Ks; it++) {
    red[tid] = attv[tid]; redi[tid] = tid; __syncthreads();
    for (int s=128;s>0;s>>=1){
      if (tid<s && red[tid+s] > red[tid]) { red[tid]=red[tid+s]; redi[tid]=redi[tid+s]; }
      __syncthreads();
    }
    kth = red[0];
    if (tid==0) attv[redi[0]] = -1e30f;
    __syncthreads();
  }
  float aout = 0.f;
  if (tid < NN) {
    aout = (av >= kth) ? av : 0.f;
    if (tid == n) aout += 1.f;
    adj[((size_t)b*NN+n)*NN + tid] = aout;
  }
  red[tid] = aout; __syncthreads();
  for (int s=128;s>0;s>>=1){ if (tid<s) red[tid]+=red[tid+s]; __syncthreads(); }
  if (tid==0) rowsum[bn] = red[0];
}

// ---------------- column sums of adj ----------------
__global__ void k_colsum(const float* __restrict__ adj, float* __restrict__ cs) {
  int b = blockIdx.x;
  for (int j=threadIdx.x; j<NN; j+=blockDim.x) {
    float s = 0.f;
    for (int i=0;i<NN;i++) s += adj[((size_t)b*NN+i)*NN + j];
    cs[(size_t)b*NN + j] = s;
  }
}

// ---------------- fused gconv via MFMA: concat + 2 merged hop phases ----------------
// P1: S1@X0 and S2@X0 (26 wave-tasks). P2: both Chebyshev combines. Barriers 5 -> 3.
__global__ __launch_bounds__(512) void k_gconv_mfma(
    const float* __restrict__ x, int bs, int ns, int din,
    const float* __restrict__ h, const float* __restrict__ ru,
    const __hip_bfloat16* __restrict__ SFH, const __hip_bfloat16* __restrict__ SFL,
    uint32_t* __restrict__ XP, int d) {
  extern __shared__ char ldsc[];
  ushort* X0H = (ushort*)ldsc;          // [KT2*QT][64][8]
  ushort* X0L = X0H + PANEL_E;
  ushort* T1H = X0L + PANEL_E;
  ushort* T1L = T1H + PANEL_E;
  ushort* T2H = T1L + PANEL_E;
  ushort* T2L = T2H + PANEL_E;
  int c0 = blockIdx.x*CHUNK;
  int b  = blockIdx.y;
  int tid = threadIdx.x;
  int l = tid & 63, wid = tid >> 6;     // 8 waves

  { uint4 z = make_uint4(0,0,0,0);
    uint4* p = (uint4*)ldsc;
    for (int i = tid; i < GCONV_LDS6/16; i += 512) p[i] = z; }
  __syncthreads();

  // concat -> X0 frag panel + global plane m=0
  for (int i = tid; i < NN*CHUNK; i += 512) {
    int n = i >> 5, cc = i & 31;
    int c = c0 + cc;
    float v = 0.f;
    if (c < din) {
      v = x[(size_t)b*bs + (size_t)n*ns + c];
    } else if (c < d) {
      int k = c - din;
      v = h[((size_t)(b*NN+n))*HH + k];
      if (ru) v *= ru[(size_t)(b*NN+n)*256 + k];
    }
    uint32_t hi, lo; splitbf(v, hi, lo);
    int kt = n >> 5, kr = n & 31;
    int ln = ((kr>>3)<<4) | (cc & 15), jj = kr & 7, q = cc >> 4;
    int fa = ((kt*QT + q)*64 + ln)*8 + jj;
    X0H[fa] = (ushort)hi; X0L[fa] = (ushort)lo;
    XP[(size_t)(b*NN+n)*XROW + c] = hi | (lo << 16);
  }
  __syncthreads();

  // P1: hop1 both sides -> T1/T2 frags + global m1/m3
  for (int task = wid; task < 2*RT2; task += 8) {
    int side = task & 1, rt = task >> 1;
    const __hip_bfloat16* AH = SFH + (size_t)(side*BB + b)*SFRAG_PER_B;
    const __hip_bfloat16* AL = SFL + (size_t)(side*BB + b)*SFRAG_PER_B;
    ushort* TH = side ? T2H : T1H;
    ushort* TL = side ? T2L : T1L;
    int mout = 1 + 2*side;
    f32x4 acc[QT];
    #pragma unroll
    for (int q=0;q<QT;q++) acc[q] = (f32x4){0.f,0.f,0.f,0.f};
    for (int kt = 0; kt < KT2; kt++) {
      size_t aoff = ((size_t)(rt*KT2+kt)*64 + l)*8;
      bf16x8 ah = *(const bf16x8*)(AH + aoff);
      bf16x8 al = *(const bf16x8*)(AL + aoff);
      #pragma unroll
      for (int q=0;q<QT;q++) {
        int boff = ((kt*QT+q)*64 + l)*8;
        bf16x8 bh = *(const bf16x8*)(X0H + boff);
        bf16x8 bl = *(const bf16x8*)(X0L + boff);
        acc[q] = __builtin_amdgcn_mfma_f32_16x16x32_bf16(ah, bl, acc[q], 0, 0, 0);
        acc[q] = __builtin_amdgcn_mfma_f32_16x16x32_bf16(al, bh, acc[q], 0, 0, 0);
        acc[q] = __builtin_amdgcn_mfma_f32_16x16x32_bf16(ah, bh, acc[q], 0, 0, 0);
      }
    }
    int colb = l & 15;
    #pragma unroll
    for (int q=0;q<QT;q++) {
      int cc = q*16 + colb;
      #pragma unroll
      for (int r=0;r<4;r++) {
        int n = rt*16 + ((l>>4)<<2) + r;
        float v = acc[q][r];
        int kt2 = n >> 5, kr = n & 31;
        int ln = ((kr>>3)<<4) | colb, jj = kr & 7;
        int fa = ((kt2*QT + q)*64 + ln)*8 + jj;
        uint32_t hi, lo; splitbf(v, hi, lo);
        TH[fa] = (ushort)hi; TL[fa] = (ushort)lo;
        if (n < NN)
          XP[(size_t)mout*MSTRIDE + (size_t)(b*NN+n)*XROW + c0 + cc] = hi | (lo << 16);
      }
    }
  }
  __syncthreads();

  // P2: cheb both sides -> global m2/m4
  for (int task = wid; task < 2*RT2; task += 8) {
    int side = task & 1, rt = task >> 1;
    const __hip_bfloat16* AH = SFH + (size_t)(side*BB + b)*SFRAG_PER_B;
    const __hip_bfloat16* AL = SFL + (size_t)(side*BB + b)*SFRAG_PER_B;
    const ushort* BH = side ? T2H : T1H;
    const ushort* BL = side ? T2L : T1L;
    int mout = 2 + 2*side;
    f32x4 acc[QT];
    #pragma unroll
    for (int q=0;q<QT;q++) acc[q] = (f32x4){0.f,0.f,0.f,0.f};
    for (int kt = 0; kt < KT2; kt++) {
      size_t aoff = ((size_t)(rt*KT2+kt)*64 + l)*8;
      bf16x8 ah = *(const bf16x8*)(AH + aoff);
      bf16x8 al = *(const bf16x8*)(AL + aoff);
      #pragma unroll
      for (int q=0;q<QT;q++) {
        int boff = ((kt*QT+q)*64 + l)*8;
        bf16x8 bh = *(const bf16x8*)(BH + boff);
        bf16x8 bl = *(const bf16x8*)(BL + boff);
        acc[q] = __builtin_amdgcn_mfma_f32_16x16x32_bf16(ah, bl, acc[q], 0, 0, 0);
        acc[q] = __builtin_amdgcn_mfma_f32_16x16x32_bf16(al, bh, acc[q], 0, 0, 0);
        acc[q] = __builtin_amdgcn_mfma_f32_16x16x32_bf16(ah, bh, acc[q], 0, 0, 0);
      }
    }
    int colb = l & 15;
    #pragma unroll
    for (int q=0;q<QT;q++) {
      int cc = q*16 + colb;
      #pragma unroll
      for (int r=0;r<4;r++) {
        int n = rt*16 + ((l>>4)<<2) + r;
        float v = acc[q][r];
        int kt2 = n >> 5, kr = n & 31;
        int ln = ((kr>>3)<<4) | colb, jj = kr & 7;
        int fa = ((kt2*QT + q)*64 + ln)*8 + jj;
        uint32_t h2 = X0H[fa], l2 = X0L[fa];
        v = 2.f*v - (bfu(h2) + bfu(l2));
        uint32_t hi, lo; splitbf(v, hi, lo);
        if (n < NN)
          XP[(size_t)mout*MSTRIDE + (size_t)(b*NN+n)*XROW + c0 + cc] = hi | (lo << 16);
      }
    }
  }
}

// ---------------- dense via split-bf16 MFMA, ping-pong LDS-staged A ------------------
// PATH 0 (gate, 32-row blocks):  RU = sigmoid(v)            (OUT=256, grid (NB/32,2))
// PATH 1 (cand, 16-row blocks):  hnew = u*h + (1-u)*tanh(v) (OUT=128, grid (NB/16,1))
//                                 + optional fused proj
template<int OUT, int PATH>
__global__ __launch_bounds__(256) void k_dense_mfma(
    const uint32_t* __restrict__ XP,
    const __hip_bfloat16* __restrict__ Wfh, const __hip_bfloat16* __restrict__ Wfl,
    const float* __restrict__ bias, int d_pad,
    float* __restrict__ RU, const float* __restrict__ h, float* __restrict__ hnew,
    const float* __restrict__ pW, const float* __restrict__ pb,
    float* __restrict__ out, float* __restrict__ decx, int t) {
  constexpr int ROWS  = (PATH==0) ? 32 : 16;
  constexpr int NQ    = (PATH==0) ? 4  : 2;
  constexpr int MAXIT = (PATH==0) ? 4  : 2;
  __shared__ ushort SA[2][2*ROWS*256];
  int tid = threadIdx.x;
  int w = tid >> 6, l = tid & 63;
  int rblk = blockIdx.x*ROWS;
  int rbase = (PATH==0) ? (w&1)*16 : 0;
  int cbase = (PATH==0) ? ((int)blockIdx.y*128 + (w>>1)*64) : (w*NQ*16);
  const int NT = OUT >> 4;
  int KT = d_pad >> 5;
  f32x4 acc[NQ];
  #pragma unroll
  for (int q=0;q<NQ;q++) acc[q] = (f32x4){0.f,0.f,0.f,0.f};
  size_t boff = (((size_t)(cbase>>4))*64 + l)*8;
  int ngrp = d_pad >> 3;
  int total = ROWS*ngrp;
  uint4 pf0[MAXIT], pf1[MAXIT];

  auto issue = [&](int m){
    int c2 = 0;
    for (int i2 = tid; i2 < total; i2 += 256, c2++) {
      int r = i2 / ngrp, cg = i2 % ngrp;
      const uint32_t* gp = XP + (size_t)m*MSTRIDE + (size_t)(rblk+r)*XROW + cg*8;
      pf0[c2] = *(const uint4*)gp;
      pf1[c2] = *(const uint4*)(gp+4);
    }
  };
  auto commit = [&](int buf){
    ushort* SAh = SA[buf];
    ushort* SAl = SA[buf] + ROWS*256;
    int c2 = 0;
    for (int i2 = tid; i2 < total; i2 += 256, c2++) {
      int r = i2 / ngrp, cg = i2 % ngrp;
      uint4 p0 = pf0[c2], p1 = pf1[c2];
      uint4 hv, lv;
      hv.x = (p0.x & 0xffffu) | (p0.y << 16);
      hv.y = (p0.z & 0xffffu) | (p0.w << 16);
      hv.z = (p1.x & 0xffffu) | (p1.y << 16);
      hv.w = (p1.z & 0xffffu) | (p1.w << 16);
      lv.x = (p0.x >> 16) | (p0.y & 0xffff0000u);
      lv.y = (p0.z >> 16) | (p0.w & 0xffff0000u);
      lv.z = (p1.x >> 16) | (p1.y & 0xffff0000u);
      lv.w = (p1.z >> 16) | (p1.w & 0xffff0000u);
      uint32_t bo2 = ((uint32_t)(r*256 + cg*8)*2) ^ ((uint32_t)(r&7)<<4);
      *(uint4*)((char*)SAh + bo2) = hv;
      *(uint4*)((char*)SAl + bo2) = lv;
    }
  };

  issue(0); commit(0);
  for (int m=0;m<5;m++) {
    if (m < 4) issue(m+1);
    __syncthreads();
    const ushort* SAh = SA[m&1];
    const ushort* SAl = SA[m&1] + ROWS*256;
    for (int kt=0; kt<KT; kt++) {
      int rr = rbase + (l & 15);
      uint32_t fb = ((uint32_t)(rr*256 + kt*32 + (l>>4)*8)*2) ^ ((uint32_t)(rr&7)<<4);
      bf16x8 ah = *(const bf16x8*)((const char*)SAh + fb);
      bf16x8 al = *(const bf16x8*)((const char*)SAl + fb);
      size_t bo = boff + ((size_t)(m*KT + kt)*NT)*512;
      #pragma unroll
      for (int q=0;q<NQ;q++) {
        bf16x8 bh = *(const bf16x8*)(Wfh + bo + (size_t)q*512);
        bf16x8 bl = *(const bf16x8*)(Wfl + bo + (size_t)q*512);
        acc[q] = __builtin_amdgcn_mfma_f32_16x16x32_bf16(ah, bl, acc[q], 0, 0, 0);
        acc[q] = __builtin_amdgcn_mfma_f32_16x16x32_bf16(al, bh, acc[q], 0, 0, 0);
        acc[q] = __builtin_amdgcn_mfma_f32_16x16x32_bf16(ah, bh, acc[q], 0, 0, 0);
      }
    }
    if (m < 4) commit((m+1)&1);
  }
  bool doproj = (PATH==1) && (pW != nullptr);
  if (doproj) __syncthreads();          // all waves done reading SA before PH reuse
  float* PH = (float*)SA;               // [ROWS][128] tile for proj
  int drow0 = rbase + ((l>>4)<<2);
  int col0 = l & 15;
  #pragma unroll
  for (int q=0;q<NQ;q++) {
    int col = cbase + q*16 + col0;
    float bv = bias[col];
    #pragma unroll
    for (int r=0;r<4;r++) {
      int rowrel = drow0 + r;
      int row = rblk + rowrel;
      float v = acc[q][r] + bv;
      if (PATH==0) {
        RU[(size_t)row*256 + col] = sigmf(v);
      } else {
        float c = tanhf(v);
        float u = RU[(size_t)row*256 + 128 + col];
        float hv = u*h[(size_t)row*HH + col] + (1.f-u)*c;
        hnew[(size_t)row*HH + col] = hv;
        if (doproj) PH[rowrel*HH + col] = hv;
      }
    }
  }
  if (doproj) {
    __syncthreads();
    int rowrel = tid >> 4;              // 0..15
    int sub = tid & 15;
    float s = 0.f;
    const float* ph = PH + rowrel*HH + sub*8;
    #pragma unroll
    for (int c=0;c<8;c++) s += ph[c]*pW[sub*8 + c];
    s += __shfl_xor(s, 1, 64);
    s += __shfl_xor(s, 2, 64);
    s += __shfl_xor(s, 4, 64);
    s += __shfl_xor(s, 8, 64);
    if (sub == 0) {
      float pv = s + pb[0];
      int gr = rblk + rowrel;
      out[(size_t)t*NB + gr] = pv;
      decx[gr] = pv;
    }
  }
}

extern "C" void kernel_launch(void* const* d_in, const int* in_sizes, int n_in,
                              void* d_out, int out_size, void* d_ws, size_t ws_size,
                              hipStream_t stream) {
  const float* enc_in = (const float*)d_in[0];
  const float* gWih = (const float*)d_in[2];
  const float* gWhh = (const float*)d_in[3];
  const float* gbih = (const float*)d_in[4];
  const float* gbhh = (const float*)d_in[5];
  const float* attW = (const float*)d_in[6];
  const float* attb = (const float*)d_in[7];
  const float* wlc  = (const float*)d_in[8];
  const float* wkey = (const float*)d_in[9];
  const float* wqry = (const float*)d_in[10];
  const float* cWg[4] = {(const float*)d_in[11],(const float*)d_in[15],(const float*)d_in[19],(const float*)d_in[23]};
  const float* cbg[4] = {(const float*)d_in[12],(const float*)d_in[16],(const float*)d_in[20],(const float*)d_in[24]};
  const float* cWc[4] = {(const float*)d_in[13],(const float*)d_in[17],(const float*)d_in[21],(const float*)d_in[25]};
  const float* cbc[4] = {(const float*)d_in[14],(const float*)d_in[18],(const float*)d_in[22],(const float*)d_in[26]};
  const float* pW = (const float*)d_in[27];
  const float* pb = (const float*)d_in[28];
  const int* topkp = (const int*)d_in[29];
  float* out = (float*)d_out;

  const int d_full[4] = {130, 256, 129, 256};
  const int d_padv[4] = {192, 256, 192, 256};

  float* ws = (float*)d_ws;
  size_t off = 0;
  auto alloc = [&](size_t n) { float* p = ws + off; off += (n + 255) & ~(size_t)255; return p; };

  // ---- persistent allocations ----
  float* RS   = alloc(NB);
  float* CS   = alloc(NB);
  float* RU   = alloc((size_t)NB*256);
  float* H0A  = alloc((size_t)NB*HH);
  float* H0B  = alloc((size_t)NB*HH);
  float* H1A  = alloc((size_t)NB*HH);
  float* H1B  = alloc((size_t)NB*HH);
  float* DECX = alloc(NB);
  float* WHHT = alloc((size_t)3*HH*HH);
  __hip_bfloat16* SFH = (__hip_bfloat16*)alloc((size_t)2*BB*SFRAG_PER_B/2);
  __hip_bfloat16* SFL = (__hip_bfloat16*)alloc((size_t)2*BB*SFRAG_PER_B/2);
  __hip_bfloat16 *WGFh[4], *WGFl[4], *WCFh[4], *WCFl[4];
  for (int p=0;p<4;p++) {
    WGFh[p] = (__hip_bfloat16*)alloc((size_t)5*d_padv[p]*256/2);
    WGFl[p] = (__hip_bfloat16*)alloc((size_t)5*d_padv[p]*256/2);
    WCFh[p] = (__hip_bfloat16*)alloc((size_t)5*d_padv[p]*128/2);
    WCFl[p] = (__hip_bfloat16*)alloc((size_t)5*d_padv[p]*128/2);
  }

  // ---- union region: supports-phase scratch OR cell-phase packed X planes ----
  const size_t SUP_SZ = (size_t)T_INC*NN*BB*HH   // OUTS
                      + (size_t)NB*HH            // POOL
                      + (size_t)NB*DHALF*2       // KEYM,QMM
                      + (size_t)BB*NN*NN + 4096; // ADJ + pad
  const size_t CELL_SZ = 5*MSTRIDE + 4096;       // XP (u32 per elem)
  float* UNION = alloc(SUP_SZ > CELL_SZ ? SUP_SZ : CELL_SZ);
  // supports view
  float* OUTS = UNION;
  float* POOL = OUTS + (size_t)T_INC*NN*BB*HH;
  float* KEYM = POOL + (size_t)NB*HH;
  float* QMM  = KEYM + (size_t)NB*DHALF;
  float* ADJ  = QMM  + (size_t)NB*DHALF;
  // cells view
  uint32_t* XP = (uint32_t*)UNION;               // 5 packed planes

  if (off*sizeof(float) > ws_size) return;

  hipMemsetAsync(H0A, 0, (size_t)NB*HH*sizeof(float), stream);
  hipMemsetAsync(H1A, 0, (size_t)NB*HH*sizeof(float), stream);
  hipMemsetAsync(DECX, 0, (size_t)NB*sizeof(float), stream);

  // ---- prep: weight transforms ----
  k_whhT<<<(3*HH*HH+255)/256, 256, 0, stream>>>(gWhh, WHHT);
  for (int p=0;p<4;p++) {
    int tg = 5*d_padv[p]*256;
    k_wshuf<<<(tg+255)/256, 256, 0, stream>>>(cWg[p], WGFh[p], WGFl[p], d_full[p], d_padv[p], 256);
    int tc = 5*d_padv[p]*128;
    k_wshuf<<<(tc+255)/256, 256, 0, stream>>>(cWc[p], WCFh[p], WCFl[p], d_full[p], d_padv[p], 128);
  }

  // ---- supports ----
  k_gru_all<<<NB/GRU_ROWS, 512, 0, stream>>>(enc_in, gWih, WHHT, gbih, gbhh, OUTS);
  k_att_pool<<<NB, 256, 0, stream>>>(OUTS, attW, attb, wlc, POOL);
  k_keyquery<<<NB, 64, 0, stream>>>(POOL, wkey, wqry, KEYM, QMM);
  k_attn_row<<<NB, 256, 0, stream>>>(KEYM, QMM, topkp, ADJ, RS);
  k_colsum<<<BB, 256, 0, stream>>>(ADJ, CS);
  { int tot = 2*BB*208*224;
    k_sshuf<<<(tot+255)/256, 256, 0, stream>>>(ADJ, RS, CS, SFH, SFL); }

  auto gconv = [&](const float* x, int bs, int ns, int din, const float* hcur,
                   const float* ru, int pidx) {
    int d = d_full[pidx], dp = d_padv[pidx];
    dim3 gg(dp/CHUNK, BB);
    k_gconv_mfma<<<gg, 512, GCONV_LDS6, stream>>>(
        x, bs, ns, din, hcur, ru, SFH, SFL, XP, d);
  };

  auto cell = [&](const float* x, int bs, int ns, int din,
                  float** hcur, float** halt, int pidx, int t) {
    int dp = d_padv[pidx];
    // gate
    gconv(x, bs, ns, din, *hcur, nullptr, pidx);
    k_dense_mfma<256,0><<<dim3(NB/32,2),256,0,stream>>>(
        XP, WGFh[pidx], WGFl[pidx], cbg[pidx], dp, RU, nullptr, nullptr,
        nullptr, nullptr, nullptr, nullptr, 0);
    // candidate (+fused hnew, + fused proj on decoder layer 1)
    gconv(x, bs, ns, din, *hcur, RU, pidx);
    const float* ppW = (pidx == 3) ? pW : nullptr;
    k_dense_mfma<128,1><<<dim3(NB/16,1),256,0,stream>>>(
        XP, WCFh[pidx], WCFl[pidx], cbc[pidx], dp, RU, *hcur, *halt,
        ppW, pb, out, DECX, t);
    float* tswp = *hcur; *hcur = *halt; *halt = tswp;
  };

  float* h0cur = H0A; float* h0alt = H0B;
  float* h1cur = H1A; float* h1alt = H1B;

  for (int t=0;t<T_INC;t++) {
    cell(enc_in + (size_t)t*NN*DIN0, T_INC*NN*DIN0, DIN0, DIN0, &h0cur, &h0alt, 0, 0);
    cell(h0cur, NN*HH, HH, HH, &h1cur, &h1alt, 1, 0);
  }
  for (int t=0;t<T_OUTC;t++) {
    cell(DECX, NN, 1, 1, &h0cur, &h0alt, 2, t);
    cell(h0cur, NN*HH, HH, HH, &h1cur, &h1alt, 3, t);
  }
}